// Round 1
// baseline (346.577 us; speedup 1.0000x reference)
//
#include <hip/hip_runtime.h>
#include <hip/hip_bf16.h>
#include <stdint.h>
#include <stddef.h>

// Problem: out[M,N] = X[M,K] @ sign(W[N,K])^T + bias[N]
// M = B*S = 4096, N = D_OUT = 4096, K = D_IN = 4096. fp32 in/out.
#define M_DIM 4096
#define N_DIM 4096
#define K_DIM 4096

#define BM 128
#define BN 128
#define BK 32

typedef __bf16 bf16;
typedef __attribute__((ext_vector_type(4))) __bf16 bf16x4;
typedef __attribute__((ext_vector_type(8))) __bf16 bf16x8;
typedef __attribute__((ext_vector_type(4))) float f32x4;

// ---------------------------------------------------------------------------
// Prep: x fp32 -> bf16 ; w fp32 -> sign(w) in bf16. Both are 16,777,216 elems.
// ---------------------------------------------------------------------------
__global__ void prep_kernel(const float* __restrict__ x, const float* __restrict__ w,
                            bf16* __restrict__ xb, bf16* __restrict__ wb, int nv /* = n/4 */) {
    int stride = gridDim.x * blockDim.x;
    for (int idx = blockIdx.x * blockDim.x + threadIdx.x; idx < nv; idx += stride) {
        float4 xv = ((const float4*)x)[idx];
        bf16x4 xo;
        xo[0] = (bf16)xv.x; xo[1] = (bf16)xv.y; xo[2] = (bf16)xv.z; xo[3] = (bf16)xv.w;
        ((bf16x4*)xb)[idx] = xo;

        float4 wv = ((const float4*)w)[idx];
        bf16x4 wo;
        wo[0] = (bf16)((wv.x > 0.f) ? 1.f : ((wv.x < 0.f) ? -1.f : 0.f));
        wo[1] = (bf16)((wv.y > 0.f) ? 1.f : ((wv.y < 0.f) ? -1.f : 0.f));
        wo[2] = (bf16)((wv.z > 0.f) ? 1.f : ((wv.z < 0.f) ? -1.f : 0.f));
        wo[3] = (bf16)((wv.w > 0.f) ? 1.f : ((wv.w < 0.f) ? -1.f : 0.f));
        ((bf16x4*)wb)[idx] = wo;
    }
}

// ---------------------------------------------------------------------------
// GEMM: m97 structure. 256 threads = 4 waves; each wave owns a 64x64 subtile
// (4x4 grid of 16x16x32 bf16 MFMAs). global_load_lds width=16 staging.
// ---------------------------------------------------------------------------
__device__ __forceinline__ void load_lds16(const void* g, void* l) {
    __builtin_amdgcn_global_load_lds(
        (const __attribute__((address_space(1))) void*)g,
        (__attribute__((address_space(3))) void*)l, 16, 0, 0);
}

__global__ __launch_bounds__(256) void gemm_bin_kernel(const bf16* __restrict__ A,
                                                       const bf16* __restrict__ Bw,
                                                       const float* __restrict__ bias,
                                                       float* __restrict__ C) {
    // LDS tiles, row-major [row][BK], no padding (global_load_lds requires
    // lane-contiguous layout: lds chunk base + lane*16B).
    __shared__ __align__(16) bf16 As[BM * BK];   // 8 KB
    __shared__ __align__(16) bf16 Bs[BN * BK];   // 8 KB

    const int tid  = threadIdx.x;
    const int lane = tid & 63;
    const int wave = tid >> 6;
    const int wm   = wave & 1;   // wave row in 2x2 grid
    const int wn   = wave >> 1;  // wave col

    const int tileM = blockIdx.y * BM;
    const int tileN = blockIdx.x * BN;

    // --- staging address setup -------------------------------------------
    // A tile = 128 rows x 32 bf16 = 8192 B = 8 chunks of 1024 B (64 lanes x 16 B).
    // Wave w stages chunks w and w+4 of both A and B.
    // Within a chunk: lane covers row (lane>>2), elem col (lane&3)*8.
    const int c0 = wave;
    const int c1 = wave + 4;
    const int rowInC = lane >> 2;
    const int colE   = (lane & 3) * 8;

    const bf16* gA0 = A  + (size_t)(tileM + c0 * 16 + rowInC) * K_DIM + colE;
    const bf16* gA1 = A  + (size_t)(tileM + c1 * 16 + rowInC) * K_DIM + colE;
    const bf16* gB0 = Bw + (size_t)(tileN + c0 * 16 + rowInC) * K_DIM + colE;
    const bf16* gB1 = Bw + (size_t)(tileN + c1 * 16 + rowInC) * K_DIM + colE;

    bf16* lA0 = As + c0 * 512;   // 1024 B chunks (wave-uniform base)
    bf16* lA1 = As + c1 * 512;
    bf16* lB0 = Bs + c0 * 512;
    bf16* lB1 = Bs + c1 * 512;

    f32x4 acc[4][4];
#pragma unroll
    for (int i = 0; i < 4; ++i)
#pragma unroll
        for (int j = 0; j < 4; ++j)
            acc[i][j] = (f32x4){0.f, 0.f, 0.f, 0.f};

    // Fragment LDS offsets (bf16 elements):
    // A frag i: row = wm*64 + i*16 + (lane&15), k = (lane>>4)*8  (8 consecutive)
    const int fragRowA = wm * 64 + (lane & 15);
    const int fragRowB = wn * 64 + (lane & 15);
    const int fragK    = (lane >> 4) * 8;

    const int nK = K_DIM / BK;  // 128
    for (int kt = 0; kt < nK; ++kt) {
        load_lds16(gA0, lA0);
        load_lds16(gA1, lA1);
        load_lds16(gB0, lB0);
        load_lds16(gB1, lB1);
        gA0 += BK; gA1 += BK; gB0 += BK; gB1 += BK;

        __syncthreads();  // drains vmcnt(0): staged tile visible to all waves

        bf16x8 af[4], bfr[4];
#pragma unroll
        for (int i = 0; i < 4; ++i)
            af[i] = *(const bf16x8*)&As[(fragRowA + i * 16) * BK + fragK];
#pragma unroll
        for (int j = 0; j < 4; ++j)
            bfr[j] = *(const bf16x8*)&Bs[(fragRowB + j * 16) * BK + fragK];

#pragma unroll
        for (int i = 0; i < 4; ++i)
#pragma unroll
            for (int j = 0; j < 4; ++j)
                acc[i][j] = __builtin_amdgcn_mfma_f32_16x16x32_bf16(af[i], bfr[j], acc[i][j], 0, 0, 0);

        __syncthreads();  // compute done before next iteration overwrites LDS
    }

    // --- epilogue: C/D layout col = lane&15, row = (lane>>4)*4 + reg ------
#pragma unroll
    for (int j = 0; j < 4; ++j) {
        const int col = tileN + wn * 64 + j * 16 + (lane & 15);
        const float bv = bias[col];
#pragma unroll
        for (int i = 0; i < 4; ++i) {
            const int row0 = tileM + wm * 64 + i * 16 + ((lane >> 4) << 2);
#pragma unroll
            for (int r = 0; r < 4; ++r) {
                C[(size_t)(row0 + r) * N_DIM + col] = acc[i][j][r] + bv;
            }
        }
    }
}

// ---------------------------------------------------------------------------
extern "C" void kernel_launch(void* const* d_in, const int* in_sizes, int n_in,
                              void* d_out, int out_size, void* d_ws, size_t ws_size,
                              hipStream_t stream) {
    const float* x    = (const float*)d_in[0];  // [2,2048,4096] = [M,K]
    const float* w    = (const float*)d_in[1];  // [4096,4096]   = [N,K]
    const float* bias = (const float*)d_in[2];  // [4096]
    float* out        = (float*)d_out;          // [M,N]

    const int nElem = M_DIM * K_DIM;            // 16,777,216 (same for x and w)
    bf16* xb = (bf16*)d_ws;                     // 32 MB
    bf16* wb = xb + (size_t)nElem;              // 32 MB

    prep_kernel<<<4096, 256, 0, stream>>>(x, w, xb, wb, nElem / 4);

    dim3 grid(N_DIM / BN, M_DIM / BM);          // 32 x 32
    gemm_bin_kernel<<<grid, 256, 0, stream>>>(xb, wb, bias, out);
}